// Round 19
// baseline (392.279 us; speedup 1.0000x reference)
//
#include <hip/hip_runtime.h>

#define NSTEPS 80
#define BATCH  65536
#define NIN    20
#define NHID   10
#define NOUT   2

// Non-temporal 8B store — outputs are write-once; keep them out of L2.
__device__ __forceinline__ void st_nt2(float* p, float2 v) {
  union { float2 f; double d; } u; u.f = v;
  __builtin_nontemporal_store(u.d, reinterpret_cast<double*>(p));
}

// Per-quad hidden-neuron split: lane q owns rows [row0[q], row0[q]+cnt[q])
__device__ __constant__ int c_row0[4] = {0, 3, 6, 8};

// All-gather of a float4 window across the 4 lanes of a quad (lanes 4e+q).
// After: G[a][c] = quad-lane a's V[c]. Bits are MOVED via shfl_xor -> exact.
__device__ __forceinline__ void quad_allgather4(float (&G)[4][4],
                                                const float4 V, int q) {
  float v[4] = {V.x, V.y, V.z, V.w};
  float u[4], p[4], w[4];
#pragma unroll
  for (int c = 0; c < 4; ++c) u[c] = __shfl_xor(v[c], 1);  // lane q^1's V
#pragma unroll
  for (int c = 0; c < 4; ++c) p[c] = __shfl_xor(v[c], 2);  // lane q^2's V
#pragma unroll
  for (int c = 0; c < 4; ++c) w[c] = __shfl_xor(u[c], 2);  // lane q^3's V
  // route into source-lane order: source a sits in reg m = q ^ a
#pragma unroll
  for (int a = 0; a < 4; ++a) {
#pragma unroll
    for (int c = 0; c < 4; ++c) {
      const int m = q ^ a;   // which local reg holds source a
      G[a][c] = (m == 0) ? v[c] : (m == 1) ? u[c] : (m == 2) ? p[c] : w[c];
    }
  }
}

// 4 threads per batch element -> 262144 threads = 4096 waves = 4 waves/SIMD
// (needs <=128 VGPR: W1 lives in LDS, per-lane state is quartered).
// VERIFIED NUMERICS (R15) preserved bit-exactly: zero-init ascending-k
// fused-FMA chains per neuron, bias after, fmaf(0.5,mem,cur)-reset,
// spike mem >= 1.0f (np.heaviside(x,1) fires at exactly-zero argument).
__global__ __launch_bounds__(256, 4)
void snn_forward4(const float* __restrict__ x,
                  const float* __restrict__ W1, const float* __restrict__ B1,
                  const float* __restrict__ W2, const float* __restrict__ B2,
                  float* __restrict__ out)
{
  __shared__ float sw1[NHID][NIN];      // 800 B; rows 80 B -> b128-aligned
  const int tid = threadIdx.x;
  if (tid < NHID * NIN) sw1[tid / NIN][tid % NIN] = W1[tid];
  __syncthreads();

  const int i = blockIdx.x * blockDim.x + tid;   // 0..4*BATCH-1
  const int b = i >> 2;
  const int q = i & 3;
  const int r0 = c_row0[q];                      // first owned hidden row
  // lanes q<2 own 3 rows, q>=2 own 2 (3rd chain runs clamped row 9, unused)
  const int r1 = r0 + 1;
  const int r2 = (q < 2) ? (r0 + 2) : 9;

  // biases for owned rows (per-lane); W2/B2 uniform -> scalar-cached
  float bb1[3];
  bb1[0] = B1[r0]; bb1[1] = B1[r1]; bb1[2] = B1[r2];
  float w2[NOUT][NHID];
#pragma unroll
  for (int o = 0; o < NOUT; ++o)
#pragma unroll
    for (int j = 0; j < NHID; ++j) w2[o][j] = W2[o * NHID + j];
  float bb2[NOUT] = {B2[0], B2[1]};

  float mem1[3] = {0.0f, 0.0f, 0.0f};
  float mem2[NOUT] = {0.0f, 0.0f};

  const size_t ss = (size_t)BATCH * NIN;
  const size_t os = (size_t)BATCH * NOUT;
  const float* xp = x + (size_t)b * NIN + 4 * q;   // own float4 window
  const float* xt = x + (size_t)b * NIN + 16;      // tail float4 (lane q=0)
  // q=0 stores spk2, q=1 stores mem2
  float* op = out + (q ? (size_t)NSTEPS * BATCH * NOUT : 0) + (size_t)b * NOUT;

  // double-buffered windows: V (own 16B) + T (tail 16B, loaded by q==0)
  float4 VA, VB, TA, TB;
  VA = *reinterpret_cast<const float4*>(xp);
  if (q == 0) TA = *reinterpret_cast<const float4*>(xt);
  VB = *reinterpret_cast<const float4*>(xp + ss);
  if (q == 0) TB = *reinterpret_cast<const float4*>(xt + ss);

#define SNN_STEP(VW, TW)                                                     \
  {                                                                          \
    /* assemble xb[0..19]: 16 from quad all-gather + 4 from tail bcast */    \
    float G[4][4];                                                           \
    quad_allgather4(G, VW, q);                                               \
    float xb[NIN];                                                           \
    _Pragma("unroll")                                                        \
    for (int a = 0; a < 4; ++a)                                              \
      _Pragma("unroll")                                                      \
      for (int c = 0; c < 4; ++c) xb[4 * a + c] = G[a][c];                   \
    {                                                                        \
      float tv[4] = {TW.x, TW.y, TW.z, TW.w};                                \
      float t1[4], t2[4], t3[4];                                             \
      _Pragma("unroll")                                                      \
      for (int c = 0; c < 4; ++c) t1[c] = __shfl_xor(tv[c], 1);              \
      _Pragma("unroll")                                                      \
      for (int c = 0; c < 4; ++c) t2[c] = __shfl_xor(tv[c], 2);              \
      _Pragma("unroll")                                                      \
      for (int c = 0; c < 4; ++c) t3[c] = __shfl_xor(t1[c], 2);              \
      _Pragma("unroll")                                                      \
      for (int c = 0; c < 4; ++c)                                            \
        xb[16 + c] = (q == 0) ? tv[c] : (q == 1) ? t1[c]                     \
                   : (q == 2) ? t2[c] : t3[c];                               \
    }                                                                        \
    /* layer 1: own (<=3) full 20-FMA chains, LDS-broadcast weights */       \
    float sp[3];                                                             \
    const int rows[3] = {r0, r1, r2};                                        \
    _Pragma("unroll")                                                        \
    for (int n = 0; n < 3; ++n) {                                            \
      float acc = 0.0f;                                                      \
      _Pragma("unroll")                                                      \
      for (int k = 0; k < NIN; ++k) acc = fmaf(xb[k], sw1[rows[n]][k], acc); \
      const float cur = acc + bb1[n];                                        \
      const float reset = (mem1[n] >= 1.0f) ? 1.0f : 0.0f;                   \
      const float m = fmaf(0.5f, mem1[n], cur) - reset;                      \
      mem1[n] = m;                                                           \
      sp[n] = (m >= 1.0f) ? 1.0f : 0.0f;                                     \
    }                                                                        \
    /* all-gather spikes: s[10] in canonical neuron order */                 \
    float su[3], sP[3], sw_[3];                                              \
    _Pragma("unroll")                                                        \
    for (int n = 0; n < 3; ++n) su[n] = __shfl_xor(sp[n], 1);                \
    _Pragma("unroll")                                                        \
    for (int n = 0; n < 3; ++n) sP[n] = __shfl_xor(sp[n], 2);                \
    _Pragma("unroll")                                                        \
    for (int n = 0; n < 3; ++n) sw_[n] = __shfl_xor(su[n], 2);               \
    float s[NHID];                                                           \
    _Pragma("unroll")                                                        \
    for (int j = 0; j < NHID; ++j) {                                         \
      const int qs = (j < 3) ? 0 : (j < 6) ? 1 : (j < 8) ? 2 : 3;            \
      const int n  = (j < 3) ? j : (j < 6) ? j - 3 : (j < 8) ? j - 6 : j - 8;\
      const int m  = q ^ qs;                                                 \
      s[j] = (m == 0) ? sp[n] : (m == 1) ? su[n] : (m == 2) ? sP[n] : sw_[n];\
    }                                                                        \
    /* layer 2: identical on all lanes */                                    \
    _Pragma("unroll")                                                        \
    for (int o = 0; o < NOUT; ++o) {                                         \
      float acc = 0.0f;                                                      \
      _Pragma("unroll")                                                      \
      for (int j = 0; j < NHID; ++j) acc = fmaf(s[j], w2[o][j], acc);        \
      const float cur = acc + bb2[o];                                        \
      const float reset = (mem2[o] >= 1.0f) ? 1.0f : 0.0f;                   \
      mem2[o] = fmaf(0.5f, mem2[o], cur) - reset;                            \
    }                                                                        \
    if (q < 2) {                                                             \
      const float2 v = q ? make_float2(mem2[0], mem2[1])                     \
                         : make_float2((mem2[0] >= 1.0f) ? 1.0f : 0.0f,      \
                                       (mem2[1] >= 1.0f) ? 1.0f : 0.0f);     \
      st_nt2(op, v);                                                         \
    }                                                                        \
    op += os;                                                                \
  }

  for (int t = 0; t < NSTEPS; t += 2) {
    SNN_STEP(VA, TA);
    if (t + 2 < NSTEPS) {
      VA = *reinterpret_cast<const float4*>(xp + (size_t)(t + 2) * ss);
      if (q == 0) TA = *reinterpret_cast<const float4*>(xt + (size_t)(t + 2) * ss);
    }
    SNN_STEP(VB, TB);
    if (t + 3 < NSTEPS) {
      VB = *reinterpret_cast<const float4*>(xp + (size_t)(t + 3) * ss);
      if (q == 0) TB = *reinterpret_cast<const float4*>(xt + (size_t)(t + 3) * ss);
    }
  }
#undef SNN_STEP
}

extern "C" void kernel_launch(void* const* d_in, const int* in_sizes, int n_in,
                              void* d_out, int out_size, void* d_ws, size_t ws_size,
                              hipStream_t stream) {
  (void)in_sizes; (void)n_in; (void)d_ws; (void)ws_size; (void)out_size;
  const float* x  = (const float*)d_in[0];
  const float* W1 = (const float*)d_in[1];
  const float* B1 = (const float*)d_in[2];
  const float* W2 = (const float*)d_in[3];
  const float* B2 = (const float*)d_in[4];
  float* out = (float*)d_out;

  dim3 grid(4 * BATCH / 256), block(256);
  snn_forward4<<<grid, block, 0, stream>>>(x, W1, B1, W2, B2, out);
}

// Round 20
// 117.876 us; speedup vs baseline: 3.3279x; 3.3279x over previous
//
#include <hip/hip_runtime.h>

#define NSTEPS 80
#define BATCH  65536
#define NIN    20
#define NHID   10
#define NOUT   2

// Non-temporal 8B store — outputs are write-once; keep them out of L2.
__device__ __forceinline__ void st_nt2(float* p, float2 v) {
  union { float2 f; double d; } u; u.f = v;
  __builtin_nontemporal_store(u.d, reinterpret_cast<double*>(p));
}

// 4 threads per batch element -> 4096 waves = 4 waves/SIMD (vs 2 in R18).
// Fixes vs failed R19: weights in VGPRs (no LDS on the FMA path, no row
// indirection); canonical-order gathers via absolute-lane __shfl
// (ds_bpermute) instead of q-dependent cndmask chains; shared-address tail
// load (HW broadcast) instead of divergent tail + shuffle.
// VERIFIED NUMERICS (R15) bit-exact: zero-init ascending-k fused-FMA chains,
// bias after, fmaf(0.5,mem,cur)-reset, spike mem >= 1.0f (heaviside(0)=1).
__global__ __launch_bounds__(256, 4)
void snn_forward4(const float* __restrict__ x,
                  const float* __restrict__ W1, const float* __restrict__ B1,
                  const float* __restrict__ W2, const float* __restrict__ B2,
                  float* __restrict__ out)
{
  const int i = blockIdx.x * blockDim.x + threadIdx.x;   // 0..4*BATCH-1
  const int b = i >> 2;                                   // batch element
  const int q = i & 3;                                    // quad lane
  const int qbase = (threadIdx.x & 63) & ~3;              // quad's lane0 (in wave)

  // hidden-row ownership: q0:{0,1,2} q1:{3,4,5} q2:{6,7,(9 dummy)} q3:{8,9,(9 dummy)}
  const int r0 = (q < 2) ? (3 * q) : (2 * q + 2);         // 0,3,6,8
  const int r1 = r0 + 1;
  const int r2 = (q < 2) ? (r0 + 2) : 9;                  // 2,5,9,9

  // per-lane weights for owned rows (60 VGPR), one-time load
  float w1[3][NIN];
  {
    const int rows[3] = {r0, r1, r2};
#pragma unroll
    for (int n = 0; n < 3; ++n)
#pragma unroll
      for (int c = 0; c < NIN; c += 4) {
        const float4 v = *reinterpret_cast<const float4*>(W1 + rows[n] * NIN + c);
        w1[n][c] = v.x; w1[n][c + 1] = v.y; w1[n][c + 2] = v.z; w1[n][c + 3] = v.w;
      }
  }
  float bb1[3] = {B1[r0], B1[r1], B1[r2]};
  // W2/B2: uniform addresses -> compiler scalarizes to SGPRs
  float w2[NOUT][NHID];
#pragma unroll
  for (int o = 0; o < NOUT; ++o)
#pragma unroll
    for (int j = 0; j < NHID; ++j) w2[o][j] = W2[o * NHID + j];
  float bb2[NOUT] = {B2[0], B2[1]};

  float mem1[3] = {0.0f, 0.0f, 0.0f};
  float mem2[NOUT] = {0.0f, 0.0f};

  const size_t ss = (size_t)BATCH * NIN;
  const size_t os = (size_t)BATCH * NOUT;
  const float* xv = x + (size_t)b * NIN + 4 * q;   // own 16B window (k=4q..4q+3)
  const float* xt = x + (size_t)b * NIN + 16;      // tail 16B, same addr in quad
  // q0 stores spk2, q1 stores mem2; q2/q3 store nothing
  float* op = out + ((q == 1) ? (size_t)NSTEPS * BATCH * NOUT : 0) + (size_t)b * NOUT;

  float4 VA = *reinterpret_cast<const float4*>(xv);
  float4 TA = *reinterpret_cast<const float4*>(xt);
  float4 VB = *reinterpret_cast<const float4*>(xv + ss);
  float4 TB = *reinterpret_cast<const float4*>(xt + ss);

#define SNN_STEP(VW, TW)                                                     \
  {                                                                          \
    /* layer 1: 3 chains, ascending k; x gathered canonical via bpermute */  \
    float acc0 = 0.0f, acc1 = 0.0f, acc2 = 0.0f;                             \
    _Pragma("unroll")                                                        \
    for (int a = 0; a < 4; ++a) {                                            \
      float g0 = __shfl(VW.x, qbase + a);                                    \
      float g1 = __shfl(VW.y, qbase + a);                                    \
      float g2 = __shfl(VW.z, qbase + a);                                    \
      float g3 = __shfl(VW.w, qbase + a);                                    \
      acc0 = fmaf(g0, w1[0][4*a+0], acc0);                                   \
      acc1 = fmaf(g0, w1[1][4*a+0], acc1);                                   \
      acc2 = fmaf(g0, w1[2][4*a+0], acc2);                                   \
      acc0 = fmaf(g1, w1[0][4*a+1], acc0);                                   \
      acc1 = fmaf(g1, w1[1][4*a+1], acc1);                                   \
      acc2 = fmaf(g1, w1[2][4*a+1], acc2);                                   \
      acc0 = fmaf(g2, w1[0][4*a+2], acc0);                                   \
      acc1 = fmaf(g2, w1[1][4*a+2], acc1);                                   \
      acc2 = fmaf(g2, w1[2][4*a+2], acc2);                                   \
      acc0 = fmaf(g3, w1[0][4*a+3], acc0);                                   \
      acc1 = fmaf(g3, w1[1][4*a+3], acc1);                                   \
      acc2 = fmaf(g3, w1[2][4*a+3], acc2);                                   \
    }                                                                        \
    /* tail k=16..19: every lane holds TW (same-addr broadcast load) */      \
    acc0 = fmaf(TW.x, w1[0][16], acc0); acc1 = fmaf(TW.x, w1[1][16], acc1);  \
    acc2 = fmaf(TW.x, w1[2][16], acc2);                                      \
    acc0 = fmaf(TW.y, w1[0][17], acc0); acc1 = fmaf(TW.y, w1[1][17], acc1);  \
    acc2 = fmaf(TW.y, w1[2][17], acc2);                                      \
    acc0 = fmaf(TW.z, w1[0][18], acc0); acc1 = fmaf(TW.z, w1[1][18], acc1);  \
    acc2 = fmaf(TW.z, w1[2][18], acc2);                                      \
    acc0 = fmaf(TW.w, w1[0][19], acc0); acc1 = fmaf(TW.w, w1[1][19], acc1);  \
    acc2 = fmaf(TW.w, w1[2][19], acc2);                                      \
    float sp0, sp1, sp2;                                                     \
    {                                                                        \
      const float cur = acc0 + bb1[0];                                       \
      const float reset = (mem1[0] >= 1.0f) ? 1.0f : 0.0f;                   \
      const float m = fmaf(0.5f, mem1[0], cur) - reset;                      \
      mem1[0] = m; sp0 = (m >= 1.0f) ? 1.0f : 0.0f;                          \
    }                                                                        \
    {                                                                        \
      const float cur = acc1 + bb1[1];                                       \
      const float reset = (mem1[1] >= 1.0f) ? 1.0f : 0.0f;                   \
      const float m = fmaf(0.5f, mem1[1], cur) - reset;                      \
      mem1[1] = m; sp1 = (m >= 1.0f) ? 1.0f : 0.0f;                          \
    }                                                                        \
    {                                                                        \
      const float cur = acc2 + bb1[2];                                       \
      const float reset = (mem1[2] >= 1.0f) ? 1.0f : 0.0f;                   \
      const float m = fmaf(0.5f, mem1[2], cur) - reset;                      \
      mem1[2] = m; sp2 = (m >= 1.0f) ? 1.0f : 0.0f;                          \
    }                                                                        \
    /* spike all-gather, canonical neuron order (10 bpermutes) */            \
    float s[NHID];                                                           \
    s[0] = __shfl(sp0, qbase + 0); s[1] = __shfl(sp1, qbase + 0);            \
    s[2] = __shfl(sp2, qbase + 0);                                           \
    s[3] = __shfl(sp0, qbase + 1); s[4] = __shfl(sp1, qbase + 1);            \
    s[5] = __shfl(sp2, qbase + 1);                                           \
    s[6] = __shfl(sp0, qbase + 2); s[7] = __shfl(sp1, qbase + 2);            \
    s[8] = __shfl(sp0, qbase + 3); s[9] = __shfl(sp1, qbase + 3);            \
    /* layer 2: identical on all lanes */                                    \
    _Pragma("unroll")                                                        \
    for (int o = 0; o < NOUT; ++o) {                                         \
      float acc = 0.0f;                                                      \
      _Pragma("unroll")                                                      \
      for (int j = 0; j < NHID; ++j) acc = fmaf(s[j], w2[o][j], acc);        \
      const float cur = acc + bb2[o];                                        \
      const float reset = (mem2[o] >= 1.0f) ? 1.0f : 0.0f;                   \
      mem2[o] = fmaf(0.5f, mem2[o], cur) - reset;                            \
    }                                                                        \
    if (q < 2) {                                                             \
      const float2 v = q ? make_float2(mem2[0], mem2[1])                     \
                         : make_float2((mem2[0] >= 1.0f) ? 1.0f : 0.0f,      \
                                       (mem2[1] >= 1.0f) ? 1.0f : 0.0f);     \
      st_nt2(op, v);                                                         \
    }                                                                        \
    op += os;                                                                \
  }

  for (int t = 0; t < NSTEPS; t += 2) {
    SNN_STEP(VA, TA);
    if (t + 2 < NSTEPS) {
      VA = *reinterpret_cast<const float4*>(xv + (size_t)(t + 2) * ss);
      TA = *reinterpret_cast<const float4*>(xt + (size_t)(t + 2) * ss);
    }
    SNN_STEP(VB, TB);
    if (t + 3 < NSTEPS) {
      VB = *reinterpret_cast<const float4*>(xv + (size_t)(t + 3) * ss);
      TB = *reinterpret_cast<const float4*>(xt + (size_t)(t + 3) * ss);
    }
  }
#undef SNN_STEP
}

extern "C" void kernel_launch(void* const* d_in, const int* in_sizes, int n_in,
                              void* d_out, int out_size, void* d_ws, size_t ws_size,
                              hipStream_t stream) {
  (void)in_sizes; (void)n_in; (void)d_ws; (void)ws_size; (void)out_size;
  const float* x  = (const float*)d_in[0];
  const float* W1 = (const float*)d_in[1];
  const float* B1 = (const float*)d_in[2];
  const float* W2 = (const float*)d_in[3];
  const float* B2 = (const float*)d_in[4];
  float* out = (float*)d_out;

  dim3 grid(4 * BATCH / 256), block(256);
  snn_forward4<<<grid, block, 0, stream>>>(x, W1, B1, W2, B2, out);
}

// Round 21
// 96.689 us; speedup vs baseline: 4.0571x; 1.2191x over previous
//
#include <hip/hip_runtime.h>

#define NSTEPS 80
#define BATCH  65536
#define NIN    20
#define NHID   10
#define NOUT   2
#define NH2    5      // hidden neurons per lane (NHID/2)
#define NW     12     // floats loaded per lane per step (3 x float4 window)

typedef float v2f __attribute__((ext_vector_type(2)));

// Non-temporal 8B store — outputs are write-once; keep them out of L2.
__device__ __forceinline__ void st_nt2(float* p, float2 v) {
  union { float2 f; double d; } u; u.f = v;
  __builtin_nontemporal_store(u.d, reinterpret_cast<double*>(p));
}

// Windowed x load: lane h of a pair loads 12 of the row's 20 floats.
//   h=0: k0..11 (row+0), h=1: k8..19 (row+32B). 3 float4 each.
__device__ __forceinline__ void load_x12(float* __restrict__ W,
                                         const float* __restrict__ row, int h) {
  const float* src = row + h * 8;
#pragma unroll
  for (int c = 0; c < 3; ++c) {
    const float4 v = *reinterpret_cast<const float4*>(src + 4 * c);
    W[4 * c + 0] = v.x; W[4 * c + 1] = v.y; W[4 * c + 2] = v.z; W[4 * c + 3] = v.w;
  }
}

// Reassemble the full 20-float row from own window + partner's window.
// 12 shfl_xor(.,1) move bits; h-selects pick source. Bits MOVED, never
// recomputed -> bit-identical numerics.
__device__ __forceinline__ void gather_x20(float (&xb)[NIN],
                                           const float (&W)[NW], int h) {
  float R[NW];
#pragma unroll
  for (int j = 0; j < NW; ++j) R[j] = __shfl_xor(W[j], 1);
#pragma unroll
  for (int k = 0; k < 8; ++k)  xb[k]      = h ? R[k]     : W[k];      // k0..7
#pragma unroll
  for (int k = 0; k < 4; ++k)  xb[8 + k]  = h ? W[k]     : W[8 + k];  // k8..11
#pragma unroll
  for (int k = 0; k < 4; ++k)  xb[12 + k] = h ? W[4 + k] : R[4 + k];  // k12..15
#pragma unroll
  for (int k = 0; k < 4; ++k)  xb[16 + k] = h ? W[8 + k] : R[8 + k];  // k16..19
}

// One SNN timestep, 2 lanes per batch element (split by hidden neuron).
// VERIFIED NUMERICS (R15) bit-exact. Packed-FMA twist: neuron chains are
// packed PAIRWISE into v2f accumulators -> v_pk_fma_f32 (2 independent IEEE
// FMAs/instr). Each neuron's chain stays sequential ascending-k with its own
// accumulator lane -> identical rounding to the scalar chain.
__device__ __forceinline__ void snn_step2(
    const float (&xb)[NIN], int h,
    const v2f (&w1p)[2][NIN], const float (&w1s)[NIN], const float (&bb1)[NH2],
    const v2f (&w2p)[NHID], const float (&bb2)[NOUT],
    float (&mem1)[NH2], float (&mem2)[NOUT],
    float2& spk_out, float2& mem_out)
{
  // layer 1: neurons (0,1) and (2,3) packed, neuron 4 scalar
  v2f a01; a01.x = 0.0f; a01.y = 0.0f;
  v2f a23; a23.x = 0.0f; a23.y = 0.0f;
  float a4 = 0.0f;
#pragma unroll
  for (int k = 0; k < NIN; ++k) {
    v2f xk; xk.x = xb[k]; xk.y = xb[k];
    a01 = __builtin_elementwise_fma(xk, w1p[0][k], a01);
    a23 = __builtin_elementwise_fma(xk, w1p[1][k], a23);
    a4  = fmaf(xb[k], w1s[k], a4);
  }
  const float accs[NH2] = {a01.x, a01.y, a23.x, a23.y, a4};
  float a[NH2];
#pragma unroll
  for (int jj = 0; jj < NH2; ++jj) {
    const float cur = accs[jj] + bb1[jj];
    const float reset = (mem1[jj] >= 1.0f) ? 1.0f : 0.0f;
    const float m = fmaf(0.5f, mem1[jj], cur) - reset;
    mem1[jj] = m;
    a[jj] = (m >= 1.0f) ? 1.0f : 0.0f;
  }
  // exchange partner's 5 spikes; assemble canonical spk1[0..9]
  float o5[NH2];
#pragma unroll
  for (int jj = 0; jj < NH2; ++jj) o5[jj] = __shfl_xor(a[jj], 1);
  float s[NHID];
#pragma unroll
  for (int j = 0; j < NH2; ++j)  s[j]       = h ? o5[j] : a[j];
#pragma unroll
  for (int j = 0; j < NH2; ++j)  s[NH2 + j] = h ? a[j]  : o5[j];
  // layer 2: both outputs packed in one v2f chain (ascending j)
  v2f c2; c2.x = 0.0f; c2.y = 0.0f;
#pragma unroll
  for (int j = 0; j < NHID; ++j) {
    v2f sj; sj.x = s[j]; sj.y = s[j];
    c2 = __builtin_elementwise_fma(sj, w2p[j], c2);
  }
#pragma unroll
  for (int o = 0; o < NOUT; ++o) {
    const float cur = ((o == 0) ? c2.x : c2.y) + bb2[o];
    const float reset = (mem2[o] >= 1.0f) ? 1.0f : 0.0f;
    mem2[o] = fmaf(0.5f, mem2[o], cur) - reset;
  }
  spk_out = make_float2((mem2[0] >= 1.0f) ? 1.0f : 0.0f,
                        (mem2[1] >= 1.0f) ? 1.0f : 0.0f);
  mem_out = make_float2(mem2[0], mem2[1]);
}

// 2 threads/elem = 2 waves/SIMD; windowed loads (no duplicate VMEM);
// packed FMA halves the dot-product issue count. ~190 VGPR at (256,2).
__global__ __launch_bounds__(256, 2)
void snn_forward2(const float* __restrict__ x,
                  const float* __restrict__ W1, const float* __restrict__ B1,
                  const float* __restrict__ W2, const float* __restrict__ B2,
                  float* __restrict__ out)
{
  const int i = blockIdx.x * blockDim.x + threadIdx.x;   // 0..2*BATCH-1
  const int b = i >> 1;
  const int h = i & 1;
  const int j0 = NH2 * h;

  // packed weights for owned rows: w1p[p][k] = (row j0+2p, row j0+2p+1)
  v2f w1p[2][NIN];
  float w1s[NIN];
#pragma unroll
  for (int p = 0; p < 2; ++p)
#pragma unroll
    for (int k = 0; k < NIN; ++k) {
      v2f t; t.x = W1[(j0 + 2 * p) * NIN + k]; t.y = W1[(j0 + 2 * p + 1) * NIN + k];
      w1p[p][k] = t;
    }
#pragma unroll
  for (int k = 0; k < NIN; ++k) w1s[k] = W1[(j0 + 4) * NIN + k];
  float bb1[NH2];
#pragma unroll
  for (int jj = 0; jj < NH2; ++jj) bb1[jj] = B1[j0 + jj];
  v2f w2p[NHID];
#pragma unroll
  for (int j = 0; j < NHID; ++j) {
    v2f t; t.x = W2[j]; t.y = W2[NHID + j];
    w2p[j] = t;
  }
  float bb2[NOUT] = {B2[0], B2[1]};

  float mem1[NH2];
#pragma unroll
  for (int jj = 0; jj < NH2; ++jj) mem1[jj] = 0.0f;
  float mem2[NOUT] = {0.0f, 0.0f};

  const size_t ss = (size_t)BATCH * NIN;
  const size_t os = (size_t)BATCH * NOUT;
  const float* xp = x + (size_t)b * NIN;
  float* op = out + (h ? (size_t)NSTEPS * BATCH * NOUT : 0) + (size_t)b * NOUT;

  float A[NW], Bb[NW], C[NW];
  load_x12(A,  xp,      h);
  load_x12(Bb, xp + ss, h);

#define SNN_STEP_EMIT(BUF)                                           \
  {                                                                  \
    float xb[NIN];                                                   \
    gather_x20(xb, BUF, h);                                          \
    float2 s_, m_;                                                   \
    snn_step2(xb, h, w1p, w1s, bb1, w2p, bb2, mem1, mem2, s_, m_);   \
    st_nt2(op, h ? m_ : s_);                                         \
    op += os;                                                        \
  }

  // 26 iters cover t=0..77 (prefetch indices <= 79: no guards needed)
  for (int t = 0; t < 78; t += 3) {
    load_x12(C,  xp + (size_t)(t + 2) * ss, h);
    SNN_STEP_EMIT(A);
    load_x12(A,  xp + (size_t)(t + 3) * ss, h);
    SNN_STEP_EMIT(Bb);
    load_x12(Bb, xp + (size_t)(t + 4) * ss, h);
    SNN_STEP_EMIT(C);
  }
  SNN_STEP_EMIT(A);   // t = 78
  SNN_STEP_EMIT(Bb);  // t = 79
#undef SNN_STEP_EMIT
}

extern "C" void kernel_launch(void* const* d_in, const int* in_sizes, int n_in,
                              void* d_out, int out_size, void* d_ws, size_t ws_size,
                              hipStream_t stream) {
  (void)in_sizes; (void)n_in; (void)d_ws; (void)ws_size; (void)out_size;
  const float* x  = (const float*)d_in[0];
  const float* W1 = (const float*)d_in[1];
  const float* B1 = (const float*)d_in[2];
  const float* W2 = (const float*)d_in[3];
  const float* B2 = (const float*)d_in[4];
  float* out = (float*)d_out;

  dim3 grid(2 * BATCH / 256), block(256);
  snn_forward2<<<grid, block, 0, stream>>>(x, W1, B1, W2, B2, out);
}